// Round 5
// baseline (143.036 us; speedup 1.0000x reference)
//
#include <hip/hip_runtime.h>
#include <hip/hip_bf16.h>
#include <hip/hip_cooperative_groups.h>
#include <stdint.h>

namespace cg = cooperative_groups;

typedef unsigned long long u64;
typedef unsigned int u32;

#define R_N 1000
#define K_N 80
#define NCOL 81           // K_N + 1 (background col)
#define TOPK_N 100
#define OUT_W 87          // 4 box + 1 score + 1 cls + 81 full scores
#define IMG_W_ 1333.0f
#define IMG_H_ 800.0f
#define CSTR 100          // per-class cand slots (first 100 kept per class provably suffice)
#define NQUAD ((R_N * NCOL) / 4)
#define NMAX 448          // fast-path NMS cap
#define WMAX 7
#define KM (K_N * CSTR)   // 8000 fixed candidate slots
#define SURV_CAP 2048

// ---- runtime input-dtype detection (round 2 proved f32; keep the shield) ----
__device__ __forceinline__ bool detect_f32(const void* scores) {
    const u64* p = (const u64*)scores;
    u64 acc = 0;
#pragma unroll
    for (int i = 0; i < 32; ++i) acc |= p[i];
    return (acc & 0x8000800080008000ull) != 0ull;
}
__device__ __forceinline__ float ldv(const void* b, int i, bool f32m) {
    if (f32m) return ((const float*)b)[i];
    return __uint_as_float((u32)(((const unsigned short*)b)[i]) << 16);
}
__device__ __forceinline__ void stv(void* o, int i, float v, bool f32m) {
    if (f32m) ((float*)o)[i] = v;
    else ((__hip_bfloat16*)o)[i] = __float2bfloat16(v);
}
__device__ __forceinline__ float4 ld4(const void* b, int i, bool f32m) {  // i % 4 == 0
    if (f32m) return ((const float4*)b)[i >> 2];
    ushort4 u = ((const ushort4*)b)[i >> 2];
    float4 f;
    f.x = __uint_as_float((u32)u.x << 16); f.y = __uint_as_float((u32)u.y << 16);
    f.z = __uint_as_float((u32)u.z << 16); f.w = __uint_as_float((u32)u.w << 16);
    return f;
}
__device__ __forceinline__ u32 f32_order(float f) {
    u32 u = __float_as_uint(f);
    return u ^ (((u32)((int)u >> 31)) | 0x80000000u);
}
__device__ __forceinline__ float f32_unorder(u32 o) {
    u32 u = (o & 0x80000000u) ? (o ^ 0x80000000u) : ~o;
    return __uint_as_float(u);
}
// bucket on high bits of the score-order field (keys: osc<<27 | inv_flat<<10 | prop)
__device__ __forceinline__ int bucket_of(u64 k) {
    int b = (int)(k >> 43) - 0xBD00;
    return b < 0 ? 0 : (b > 1023 ? 1023 : b);
}

struct P2 {                       // per-class NMS scratch (phase 2)
    float4 bx4[R_N];
    u64 key_s[R_N];
    u64 pool[NMAX * WMAX];        // ukey pre-sort / Mrow bitmatrix / keep[] fallback
    float area[R_N];
    float sc[R_N];
    u64 keep_words[16];
    int s_n;
};
struct P3 {                       // global top-100 scratch (phase 3, block 0)
    u64 keys[KM];
    u64 surv[SURV_CAP];
    u32 hist[1024];
    u32 scan[256];
    int meta[4];                  // [0]=surv count, [1]=bucket cutoff B
};
union SMEM { P2 p2; P3 p3; };

__device__ __forceinline__ void write_row(void* outp, const void* boxes, const void* scores,
                                          u64 x, int rank, bool f32m) {
    int prop = (int)(x & 0x3FFull);
    int flat = 131071 - (int)((x >> 10) & 0x1FFFFull);
    int cls = flat / R_N;
    float score = f32_unorder((u32)((x >> 27) & 0xFFFFFFFFull));
    int ob = rank * OUT_W;
    float4 bx = ld4(boxes, prop * (K_N * 4) + cls * 4, f32m);
    stv(outp, ob + 0, fminf(fmaxf(bx.x, 0.f), IMG_W_), f32m);
    stv(outp, ob + 1, fminf(fmaxf(bx.y, 0.f), IMG_H_), f32m);
    stv(outp, ob + 2, fminf(fmaxf(bx.z, 0.f), IMG_W_), f32m);
    stv(outp, ob + 3, fminf(fmaxf(bx.w, 0.f), IMG_H_), f32m);
    stv(outp, ob + 4, score, f32m);
    stv(outp, ob + 5, (float)cls, f32m);
    const int sb = prop * NCOL;
#pragma unroll 9
    for (int j = 0; j < NCOL; ++j)
        stv(outp, ob + 6 + j, ldv(scores, sb + j, f32m), f32m);
}

__global__ __launch_bounds__(256) void k_all(const void* __restrict__ boxes,
                                             const void* __restrict__ scores,
                                             float* __restrict__ hdr,
                                             u64* __restrict__ cand,
                                             void* __restrict__ outp) {
    __shared__ SMEM sm;
    __shared__ float s_sum[4], s_max[4];
    cg::grid_group grid = cg::this_grid();

    const int bid = blockIdx.x, tid = threadIdx.x;
    const int lane = tid & 63, wv = tid >> 6;
    const bool f32m = detect_f32(scores);

    // ================= phase 1: stat partials + zero d_out =================
    {
        const int zn = f32m ? (TOPK_N * OUT_W) : (TOPK_N * OUT_W / 2);
        for (int t = bid * 256 + tid; t < zn; t += K_N * 256) ((int*)outp)[t] = 0;

        float sum = 0.f, mx = -1e30f;
        int q = bid * 256 + tid;
        if (q < NQUAD) {
            float4 v = ld4(scores, q * 4, f32m);
            int m = (q * 4) % NCOL;
            float vv[4] = {v.x, v.y, v.z, v.w};
#pragma unroll
            for (int e = 0; e < 4; ++e) {
                int mm = m + e; if (mm >= NCOL) mm -= NCOL;
                if (mm != K_N) { sum += vv[e]; mx = fmaxf(mx, vv[e]); }
            }
        }
#pragma unroll
        for (int off = 32; off > 0; off >>= 1) {
            sum += __shfl_down(sum, off);
            mx = fmaxf(mx, __shfl_down(mx, off));
        }
        if (lane == 0) { s_sum[wv] = sum; s_max[wv] = mx; }
        __syncthreads();
        if (tid == 0) {
            hdr[2 * bid] = s_sum[0] + s_sum[1] + s_sum[2] + s_sum[3];
            hdr[2 * bid + 1] = fmaxf(fmaxf(s_max[0], s_max[1]), fmaxf(s_max[2], s_max[3]));
        }
    }
    grid.sync();

    // ================= phase 2: per-class NMS (block = class) ==============
    {
        const int c = bid;
        float S = 0.f, M = -1e30f;
        for (int b = 0; b < K_N; ++b) { S += hdr[2 * b]; M = fmaxf(M, hdr[2 * b + 1]); }
        const float thres = fminf(0.05f, 0.5f * (S / (float)(R_N * K_N) + M));

        // stage score column c (all 256 threads)
        for (int r = tid; r < R_N; r += 256) sm.p2.sc[r] = ldv(scores, r * NCOL + c, f32m);
        __syncthreads();

        // wave-0: ballot stream-compaction of keys (no barriers inside)
        u64* ukey = sm.p2.pool;
        const u64 below = (lane == 0) ? 0ull : (~0ull >> (64 - lane));
        if (wv == 0) {
            int nn = 0;
            for (int r0 = 0; r0 < R_N; r0 += 64) {
                int r = r0 + lane;
                bool pred = (r < R_N) && (sm.p2.sc[r] > thres);
                u64 m = __ballot(pred);
                if (pred) {
                    int slot = nn + __popcll(m & below);
                    ukey[slot] = ((u64)f32_order(sm.p2.sc[r]) << 32) | (u64)(u32)(R_N - 1 - r);
                }
                nn += __popcll(m);
            }
            if (lane == 0) sm.p2.s_n = nn;
        }
        __syncthreads();
        const int n = sm.p2.s_n;

        // counting-rank sort + box gather (all 256 threads)
        for (int j = tid; j < n; j += 256) {
            u64 kj = ukey[j];
            int rank = 0;
            for (int k = 0; k < n; ++k) rank += (ukey[k] > kj) ? 1 : 0;
            int r = (R_N - 1) - (int)(kj & 0xFFFFFFFFull);
            float4 b = ld4(boxes, r * (K_N * 4) + c * 4, f32m);
            float x1 = fminf(fmaxf(b.x, 0.f), IMG_W_);
            float y1 = fminf(fmaxf(b.y, 0.f), IMG_H_);
            float x2 = fminf(fmaxf(b.z, 0.f), IMG_W_);
            float y2 = fminf(fmaxf(b.w, 0.f), IMG_H_);
            sm.p2.key_s[rank] = kj;
            sm.p2.bx4[rank] = make_float4(x1, y1, x2, y2);
            sm.p2.area[rank] = fmaxf(x2 - x1, 0.f) * fmaxf(y2 - y1, 0.f);
        }
        __syncthreads();

        if (n <= NMAX) {
            // suppression bit-matrix, built by all 4 waves (w strided by wave)
            const int W = (n + 63) >> 6;
            u64* Mrow = sm.p2.pool;            // ukey dead after sort
            for (int w = wv; w < W; w += 4) {
                int j = w * 64 + lane;
                bool jv = j < n;
                float4 bj = jv ? sm.p2.bx4[j] : make_float4(0.f, 0.f, 0.f, 0.f);
                float aj = jv ? sm.p2.area[j] : 0.f;
                for (int i = 0; i < n; ++i) {
                    float4 bi = sm.p2.bx4[i];
                    float ai = sm.p2.area[i];
                    float xx1 = fmaxf(bi.x, bj.x), yy1 = fmaxf(bi.y, bj.y);
                    float xx2 = fminf(bi.z, bj.z), yy2 = fminf(bi.w, bj.w);
                    float inter = fmaxf(xx2 - xx1, 0.f) * fmaxf(yy2 - yy1, 0.f);
                    bool sup = jv && (j > i) &&
                               (inter / fmaxf(ai + aj - inter, 1e-9f) > 0.5f);
                    u64 m = __ballot(sup);
                    if (lane == 0) Mrow[i * W + w] = m;
                }
            }
            __syncthreads();

            // wave-0: register keep-propagation with depth-8 LDS prefetch (no barriers)
            if (wv == 0) {
                u64 keep_w = 0;
                if (lane < W) {
                    int rem = n - lane * 64;
                    keep_w = (rem >= 64) ? ~0ull : ((1ull << rem) - 1ull);
                }
                const int lw = (lane < W) ? lane : 0;
                u64 fifo[8];
#pragma unroll
                for (int d = 0; d < 8; ++d) fifo[d] = (d < n) ? Mrow[d * W + lw] : 0ull;
                for (int ib = 0; ib < n; ib += 8) {
#pragma unroll
                    for (int d = 0; d < 8; ++d) {
                        int i = ib + d;
                        if (i >= n) break;
                        u64 row = fifo[d];
                        int ip = i + 8;
                        fifo[d] = (ip < n) ? Mrow[ip * W + lw] : 0ull;
                        u64 kw = __shfl(keep_w, i >> 6);
                        if ((kw >> (i & 63)) & 1ull) keep_w &= ~row;
                    }
                }
                if (lane < W) sm.p2.keep_words[lane] = keep_w;
                if (lane >= W && lane < 16) sm.p2.keep_words[lane] = 0;
            }
        } else {
            // fallback: block-wide serial greedy (block-uniform barriers)
            int* keep = (int*)sm.p2.pool;
            for (int j = tid; j < n; j += 256) keep[j] = 1;
            __syncthreads();
            for (int i = 0; i < n - 1; ++i) {
                __syncthreads();
                if (!keep[i]) continue;
                float4 bi = sm.p2.bx4[i];
                float ai = sm.p2.area[i];
                for (int j = i + 1 + tid; j < n; j += 256) {
                    if (!keep[j]) continue;
                    float xx1 = fmaxf(bi.x, sm.p2.bx4[j].x), yy1 = fmaxf(bi.y, sm.p2.bx4[j].y);
                    float xx2 = fminf(bi.z, sm.p2.bx4[j].z), yy2 = fminf(bi.w, sm.p2.bx4[j].w);
                    float inter = fmaxf(xx2 - xx1, 0.f) * fmaxf(yy2 - yy1, 0.f);
                    if (inter / fmaxf(ai + sm.p2.area[j] - inter, 1e-9f) > 0.5f) keep[j] = 0;
                }
            }
            __syncthreads();
            if (wv == 0) {
                for (int w = 0; w < 16; ++w) {
                    int j = w * 64 + lane;
                    u64 m = __ballot((j < n) && keep[j]);
                    if (lane == 0) sm.p2.keep_words[w] = m;
                }
            }
        }
        __syncthreads();

        // wave-0: emit first <=100 kept per class, zero-pad remaining slots
        if (wv == 0) {
            int kb = 0;
            for (int j0 = 0; j0 < n; j0 += 64) {
                int j = j0 + lane;
                u64 mw = sm.p2.keep_words[j0 >> 6];
                bool kp = (j < n) && ((mw >> lane) & 1ull);
                u64 mm = __ballot(kp);
                int kr = kb + __popcll(mm & below);
                if (kp && kr < CSTR) {
                    u64 kj = sm.p2.key_s[j];
                    u32 osc = (u32)(kj >> 32);
                    int rr = (R_N - 1) - (int)(kj & 0xFFFFFFFFull);
                    int flat = c * R_N + j;
                    cand[c * CSTR + kr] =
                        ((u64)osc << 27) | ((u64)(u32)(131071 - flat) << 10) | (u64)(u32)rr;
                }
                kb += __popcll(mm);
            }
            if (kb > CSTR) kb = CSTR;
            for (int k2 = kb + lane; k2 < CSTR; k2 += 64) cand[c * CSTR + k2] = 0;
        }
    }
    grid.sync();

    // ================= phase 3: block 0 — global top-100 + output ==========
    if (bid == 0) {
        for (int t = tid; t < KM; t += 256) sm.p3.keys[t] = cand[t];
        for (int t = tid; t < 1024; t += 256) sm.p3.hist[t] = 0;
        if (tid == 0) { sm.p3.meta[0] = 0; sm.p3.meta[1] = 1024; }
        __syncthreads();

        for (int t = tid; t < KM; t += 256) {
            u64 k = sm.p3.keys[t];
            if (k) atomicAdd(&sm.p3.hist[bucket_of(k)], 1u);
        }
        __syncthreads();

        // suffix sums over 1024 buckets (4 per thread + block suffix-scan)
        u32 h[4];
#pragma unroll
        for (int i = 0; i < 4; ++i) h[i] = sm.p3.hist[4 * tid + i];
        sm.p3.scan[tid] = h[0] + h[1] + h[2] + h[3];
        __syncthreads();
        for (int off = 1; off < 256; off <<= 1) {
            u32 v = sm.p3.scan[tid] + ((tid + off < 256) ? sm.p3.scan[tid + off] : 0u);
            __syncthreads();
            sm.p3.scan[tid] = v;
            __syncthreads();
        }
        u32 total = sm.p3.scan[0];
        u32 carry = (tid < 255) ? sm.p3.scan[tid + 1] : 0u;
        u32 sfx[4];
        sfx[3] = carry + h[3];
        sfx[2] = sfx[3] + h[2];
        sfx[1] = sfx[2] + h[1];
        sfx[0] = sfx[1] + h[0];
#pragma unroll
        for (int i = 0; i < 4; ++i) sm.p3.hist[4 * tid + i] = sfx[i];
        __syncthreads();

        u32 target = total < (u32)TOPK_N ? total : (u32)TOPK_N;
        if (target > 0) {
#pragma unroll
            for (int i = 0; i < 4; ++i) {
                int b = 4 * tid + i;
                u32 sb = sm.p3.hist[b];
                u32 snext = (b < 1023) ? sm.p3.hist[b + 1] : 0u;
                if (sb >= target && snext < target) sm.p3.meta[1] = b;  // unique writer
            }
        }
        __syncthreads();
        const int B = sm.p3.meta[1];

        // compact survivors (bucket >= B); order-free, exact ranks computed below
        for (int t = tid; t < KM; t += 256) {
            u64 k = sm.p3.keys[t];
            if (k && bucket_of(k) >= B) {
                int idx = atomicAdd(&sm.p3.meta[0], 1);
                if (idx < SURV_CAP) sm.p3.surv[idx] = k;
            }
        }
        __syncthreads();
        const int Sn = sm.p3.meta[0];

        if (Sn <= SURV_CAP) {
            for (int s = tid; s < Sn; s += 256) {
                u64 x = sm.p3.surv[s];
                int rank = 0;
                for (int i = 0; i < Sn; ++i) rank += (sm.p3.surv[i] > x) ? 1 : 0;
                if (rank < TOPK_N) write_row(outp, boxes, scores, x, rank, f32m);
            }
        } else {
            // pathological fallback: rank survivors against all keys
            for (int t = tid; t < KM; t += 256) {
                u64 x = sm.p3.keys[t];
                if (x && bucket_of(x) >= B) {
                    int rank = 0;
                    for (int i = 0; i < KM; ++i) rank += (sm.p3.keys[i] > x) ? 1 : 0;
                    if (rank < TOPK_N) write_row(outp, boxes, scores, x, rank, f32m);
                }
            }
        }
    }
}

extern "C" void kernel_launch(void* const* d_in, const int* in_sizes, int n_in,
                              void* d_out, int out_size, void* d_ws, size_t ws_size,
                              hipStream_t stream) {
    const void* boxes = d_in[0];
    const void* scores = d_in[1];
    float* hdr = (float*)d_ws;                 // 160 f32 partials
    u64* cand = (u64*)((char*)d_ws + 1024);    // 8000 u64 candidate slots
    void* outp = d_out;

    void* args[] = {(void*)&boxes, (void*)&scores, (void*)&hdr, (void*)&cand, (void*)&outp};
    hipLaunchCooperativeKernel((const void*)k_all, dim3(K_N), dim3(256), args, 0, stream);
}

// Round 6
// 119.976 us; speedup vs baseline: 1.1922x; 1.1922x over previous
//
#include <hip/hip_runtime.h>
#include <hip/hip_bf16.h>
#include <stdint.h>

typedef unsigned long long u64;
typedef unsigned int u32;

#define R_N 1000
#define K_N 80
#define NCOL 81           // K_N + 1 (background col)
#define TOPK_N 100
#define OUT_W 87          // 4 box + 1 score + 1 cls + 81 full scores
#define IMG_W_ 1333.0f
#define IMG_H_ 800.0f
#define CSTR 100          // per-class cand slots (first 100 kept per class provably suffice)
#define NQUAD ((R_N * NCOL) / 4)
#define NMAX 448          // fast-path NMS cap
#define WMAX 7
#define KM (K_N * CSTR)   // 8000 fixed candidate slots
#define SURV_CAP 2048

// ---- runtime input-dtype detection (round 2 proved f32; keep the shield) ----
__device__ __forceinline__ bool detect_f32(const void* scores) {
    const u64* p = (const u64*)scores;
    u64 acc = 0;
#pragma unroll
    for (int i = 0; i < 32; ++i) acc |= p[i];
    return (acc & 0x8000800080008000ull) != 0ull;
}
__device__ __forceinline__ float ldv(const void* b, int i, bool f32m) {
    if (f32m) return ((const float*)b)[i];
    return __uint_as_float((u32)(((const unsigned short*)b)[i]) << 16);
}
__device__ __forceinline__ void stv(void* o, int i, float v, bool f32m) {
    if (f32m) ((float*)o)[i] = v;
    else ((__hip_bfloat16*)o)[i] = __float2bfloat16(v);
}
__device__ __forceinline__ float4 ld4(const void* b, int i, bool f32m) {  // i % 4 == 0
    if (f32m) return ((const float4*)b)[i >> 2];
    ushort4 u = ((const ushort4*)b)[i >> 2];
    float4 f;
    f.x = __uint_as_float((u32)u.x << 16); f.y = __uint_as_float((u32)u.y << 16);
    f.z = __uint_as_float((u32)u.z << 16); f.w = __uint_as_float((u32)u.w << 16);
    return f;
}
__device__ __forceinline__ u32 f32_order(float f) {
    u32 u = __float_as_uint(f);
    return u ^ (((u32)((int)u >> 31)) | 0x80000000u);
}
__device__ __forceinline__ float f32_unorder(u32 o) {
    u32 u = (o & 0x80000000u) ? (o ^ 0x80000000u) : ~o;
    return __uint_as_float(u);
}
// bucket on high bits of the score-order field (keys: osc<<27 | inv_flat<<10 | prop)
__device__ __forceinline__ int bucket_of(u64 k) {
    int b = (int)(k >> 43) - 0xBD00;
    return b < 0 ? 0 : (b > 1023 ? 1023 : b);
}

// software grid barrier: all 80 blocks are co-resident (1 block/CU by LDS, 80 <= 256 CUs).
// counters zeroed by hipMemsetAsync before launch; device-scope atomics cross XCD L2s.
__device__ __forceinline__ void grid_barrier(u32* bar, u32 nblk) {
    __syncthreads();
    if (threadIdx.x == 0) {
        __threadfence();   // release all prior global writes
        __hip_atomic_fetch_add(bar, 1u, __ATOMIC_ACQ_REL, __HIP_MEMORY_SCOPE_AGENT);
        while (__hip_atomic_load(bar, __ATOMIC_ACQUIRE, __HIP_MEMORY_SCOPE_AGENT) < nblk) {
            __builtin_amdgcn_s_sleep(2);
        }
    }
    __syncthreads();
}

struct P2 {                       // per-class NMS scratch (phase 2)
    float4 bx4[R_N];
    u64 key_s[R_N];
    u64 pool[NMAX * WMAX];        // ukey pre-sort / Mrow bitmatrix / keep[] fallback
    float area[R_N];
    float sc[R_N];
    u64 keep_words[16];
    int s_n;
};
struct P3 {                       // global top-100 scratch (phase 3, block 0)
    u64 keys[KM];
    u64 surv[SURV_CAP];
    u32 hist[1024];
    u32 scan[256];
    int meta[4];                  // [0]=surv count, [1]=bucket cutoff B
};
union SMEM { P2 p2; P3 p3; };

__device__ __forceinline__ void write_row(void* outp, const void* boxes, const void* scores,
                                          u64 x, int rank, bool f32m) {
    int prop = (int)(x & 0x3FFull);
    int flat = 131071 - (int)((x >> 10) & 0x1FFFFull);
    int cls = flat / R_N;
    float score = f32_unorder((u32)((x >> 27) & 0xFFFFFFFFull));
    int ob = rank * OUT_W;
    float4 bx = ld4(boxes, prop * (K_N * 4) + cls * 4, f32m);
    stv(outp, ob + 0, fminf(fmaxf(bx.x, 0.f), IMG_W_), f32m);
    stv(outp, ob + 1, fminf(fmaxf(bx.y, 0.f), IMG_H_), f32m);
    stv(outp, ob + 2, fminf(fmaxf(bx.z, 0.f), IMG_W_), f32m);
    stv(outp, ob + 3, fminf(fmaxf(bx.w, 0.f), IMG_H_), f32m);
    stv(outp, ob + 4, score, f32m);
    stv(outp, ob + 5, (float)cls, f32m);
    const int sb = prop * NCOL;
#pragma unroll 9
    for (int j = 0; j < NCOL; ++j)
        stv(outp, ob + 6 + j, ldv(scores, sb + j, f32m), f32m);
}

__global__ __launch_bounds__(256, 1) void k_all(const void* __restrict__ boxes,
                                                const void* __restrict__ scores,
                                                float* __restrict__ hdr,
                                                u32* __restrict__ bars,
                                                u64* __restrict__ cand,
                                                void* __restrict__ outp) {
    __shared__ SMEM sm;
    __shared__ float s_sum[4], s_max[4];
    __shared__ float s_thres;

    const int bid = blockIdx.x, tid = threadIdx.x;
    const int lane = tid & 63, wv = tid >> 6;
    const bool f32m = detect_f32(scores);
    const int c = bid;

    // ================= phase 1: stage score column (overlap) + stat partials + zero d_out ====
    {
        // issue phase-2 column staging first so its scattered-load latency overlaps phase 1
        for (int r = tid; r < R_N; r += 256) sm.p2.sc[r] = ldv(scores, r * NCOL + c, f32m);

        const int zn = f32m ? (TOPK_N * OUT_W) : (TOPK_N * OUT_W / 2);
        for (int t = bid * 256 + tid; t < zn; t += K_N * 256) ((int*)outp)[t] = 0;

        float sum = 0.f, mx = -1e30f;
        int q = bid * 256 + tid;
        if (q < NQUAD) {
            float4 v = ld4(scores, q * 4, f32m);
            int m = (q * 4) % NCOL;
            float vv[4] = {v.x, v.y, v.z, v.w};
#pragma unroll
            for (int e = 0; e < 4; ++e) {
                int mm = m + e; if (mm >= NCOL) mm -= NCOL;
                if (mm != K_N) { sum += vv[e]; mx = fmaxf(mx, vv[e]); }
            }
        }
#pragma unroll
        for (int off = 32; off > 0; off >>= 1) {
            sum += __shfl_down(sum, off);
            mx = fmaxf(mx, __shfl_down(mx, off));
        }
        if (lane == 0) { s_sum[wv] = sum; s_max[wv] = mx; }
        __syncthreads();
        if (tid == 0) {
            hdr[2 * bid] = s_sum[0] + s_sum[1] + s_sum[2] + s_sum[3];
            hdr[2 * bid + 1] = fmaxf(fmaxf(s_max[0], s_max[1]), fmaxf(s_max[2], s_max[3]));
        }
    }
    grid_barrier(&bars[0], K_N);

    // ================= phase 2: per-class NMS (block = class) ==============
    {
        // wave-parallel threshold reduction (80 partials; lane + lane+64)
        if (wv == 0) {
            float S = hdr[2 * lane], M = hdr[2 * lane + 1];
            if (lane + 64 < K_N) {
                S += hdr[2 * (lane + 64)];
                M = fmaxf(M, hdr[2 * (lane + 64) + 1]);
            }
#pragma unroll
            for (int off = 32; off > 0; off >>= 1) {
                S += __shfl_down(S, off);
                M = fmaxf(M, __shfl_down(M, off));
            }
            if (lane == 0)
                s_thres = fminf(0.05f, 0.5f * (S / (float)(R_N * K_N) + M));
        }
        __syncthreads();
        const float thres = s_thres;

        // wave-0: ballot stream-compaction of keys (no barriers inside)
        u64* ukey = sm.p2.pool;
        const u64 below = (lane == 0) ? 0ull : (~0ull >> (64 - lane));
        if (wv == 0) {
            int nn = 0;
            for (int r0 = 0; r0 < R_N; r0 += 64) {
                int r = r0 + lane;
                bool pred = (r < R_N) && (sm.p2.sc[r] > thres);
                u64 m = __ballot(pred);
                if (pred) {
                    int slot = nn + __popcll(m & below);
                    ukey[slot] = ((u64)f32_order(sm.p2.sc[r]) << 32) | (u64)(u32)(R_N - 1 - r);
                }
                nn += __popcll(m);
            }
            if (lane == 0) sm.p2.s_n = nn;
        }
        __syncthreads();
        const int n = sm.p2.s_n;

        // counting-rank sort + box gather (all 256 threads)
        for (int j = tid; j < n; j += 256) {
            u64 kj = ukey[j];
            int rank = 0;
            for (int k = 0; k < n; ++k) rank += (ukey[k] > kj) ? 1 : 0;
            int r = (R_N - 1) - (int)(kj & 0xFFFFFFFFull);
            float4 b = ld4(boxes, r * (K_N * 4) + c * 4, f32m);
            float x1 = fminf(fmaxf(b.x, 0.f), IMG_W_);
            float y1 = fminf(fmaxf(b.y, 0.f), IMG_H_);
            float x2 = fminf(fmaxf(b.z, 0.f), IMG_W_);
            float y2 = fminf(fmaxf(b.w, 0.f), IMG_H_);
            sm.p2.key_s[rank] = kj;
            sm.p2.bx4[rank] = make_float4(x1, y1, x2, y2);
            sm.p2.area[rank] = fmaxf(x2 - x1, 0.f) * fmaxf(y2 - y1, 0.f);
        }
        __syncthreads();

        if (n <= NMAX) {
            // suppression bit-matrix, built by all 4 waves (w strided by wave)
            const int W = (n + 63) >> 6;
            u64* Mrow = sm.p2.pool;            // ukey dead after sort
            for (int w = wv; w < W; w += 4) {
                int j = w * 64 + lane;
                bool jv = j < n;
                float4 bj = jv ? sm.p2.bx4[j] : make_float4(0.f, 0.f, 0.f, 0.f);
                float aj = jv ? sm.p2.area[j] : 0.f;
                for (int i = 0; i < n; ++i) {
                    float4 bi = sm.p2.bx4[i];
                    float ai = sm.p2.area[i];
                    float xx1 = fmaxf(bi.x, bj.x), yy1 = fmaxf(bi.y, bj.y);
                    float xx2 = fminf(bi.z, bj.z), yy2 = fminf(bi.w, bj.w);
                    float inter = fmaxf(xx2 - xx1, 0.f) * fmaxf(yy2 - yy1, 0.f);
                    bool sup = jv && (j > i) &&
                               (inter / fmaxf(ai + aj - inter, 1e-9f) > 0.5f);
                    u64 m = __ballot(sup);
                    if (lane == 0) Mrow[i * W + w] = m;
                }
            }
            __syncthreads();

            // wave-0: register keep-propagation with depth-8 LDS prefetch (no barriers)
            if (wv == 0) {
                u64 keep_w = 0;
                if (lane < W) {
                    int rem = n - lane * 64;
                    keep_w = (rem >= 64) ? ~0ull : ((1ull << rem) - 1ull);
                }
                const int lw = (lane < W) ? lane : 0;
                u64 fifo[8];
#pragma unroll
                for (int d = 0; d < 8; ++d) fifo[d] = (d < n) ? Mrow[d * W + lw] : 0ull;
                for (int ib = 0; ib < n; ib += 8) {
#pragma unroll
                    for (int d = 0; d < 8; ++d) {
                        int i = ib + d;
                        if (i >= n) break;
                        u64 row = fifo[d];
                        int ip = i + 8;
                        fifo[d] = (ip < n) ? Mrow[ip * W + lw] : 0ull;
                        u64 kw = __shfl(keep_w, i >> 6);
                        if ((kw >> (i & 63)) & 1ull) keep_w &= ~row;
                    }
                }
                if (lane < W) sm.p2.keep_words[lane] = keep_w;
                if (lane >= W && lane < 16) sm.p2.keep_words[lane] = 0;
            }
        } else {
            // fallback: block-wide serial greedy (block-uniform barriers)
            int* keep = (int*)sm.p2.pool;
            for (int j = tid; j < n; j += 256) keep[j] = 1;
            __syncthreads();
            for (int i = 0; i < n - 1; ++i) {
                __syncthreads();
                if (!keep[i]) continue;
                float4 bi = sm.p2.bx4[i];
                float ai = sm.p2.area[i];
                for (int j = i + 1 + tid; j < n; j += 256) {
                    if (!keep[j]) continue;
                    float xx1 = fmaxf(bi.x, sm.p2.bx4[j].x), yy1 = fmaxf(bi.y, sm.p2.bx4[j].y);
                    float xx2 = fminf(bi.z, sm.p2.bx4[j].z), yy2 = fminf(bi.w, sm.p2.bx4[j].w);
                    float inter = fmaxf(xx2 - xx1, 0.f) * fmaxf(yy2 - yy1, 0.f);
                    if (inter / fmaxf(ai + sm.p2.area[j] - inter, 1e-9f) > 0.5f) keep[j] = 0;
                }
            }
            __syncthreads();
            if (wv == 0) {
                for (int w = 0; w < 16; ++w) {
                    int j = w * 64 + lane;
                    u64 m = __ballot((j < n) && keep[j]);
                    if (lane == 0) sm.p2.keep_words[w] = m;
                }
            }
        }
        __syncthreads();

        // wave-0: emit first <=100 kept per class, zero-pad remaining slots
        if (wv == 0) {
            int kb = 0;
            for (int j0 = 0; j0 < n; j0 += 64) {
                int j = j0 + lane;
                u64 mw = sm.p2.keep_words[j0 >> 6];
                bool kp = (j < n) && ((mw >> lane) & 1ull);
                u64 mm = __ballot(kp);
                int kr = kb + __popcll(mm & below);
                if (kp && kr < CSTR) {
                    u64 kj = sm.p2.key_s[j];
                    u32 osc = (u32)(kj >> 32);
                    int rr = (R_N - 1) - (int)(kj & 0xFFFFFFFFull);
                    int flat = c * R_N + j;
                    cand[c * CSTR + kr] =
                        ((u64)osc << 27) | ((u64)(u32)(131071 - flat) << 10) | (u64)(u32)rr;
                }
                kb += __popcll(mm);
            }
            if (kb > CSTR) kb = CSTR;
            for (int k2 = kb + lane; k2 < CSTR; k2 += 64) cand[c * CSTR + k2] = 0;
        }
    }
    grid_barrier(&bars[1], K_N);

    // ================= phase 3: block 0 — global top-100 + output ==========
    if (bid == 0) {
        for (int t = tid; t < KM; t += 256) sm.p3.keys[t] = cand[t];
        for (int t = tid; t < 1024; t += 256) sm.p3.hist[t] = 0;
        if (tid == 0) { sm.p3.meta[0] = 0; sm.p3.meta[1] = 1024; }
        __syncthreads();

        for (int t = tid; t < KM; t += 256) {
            u64 k = sm.p3.keys[t];
            if (k) atomicAdd(&sm.p3.hist[bucket_of(k)], 1u);
        }
        __syncthreads();

        // suffix sums over 1024 buckets (4 per thread + block suffix-scan)
        u32 h[4];
#pragma unroll
        for (int i = 0; i < 4; ++i) h[i] = sm.p3.hist[4 * tid + i];
        sm.p3.scan[tid] = h[0] + h[1] + h[2] + h[3];
        __syncthreads();
        for (int off = 1; off < 256; off <<= 1) {
            u32 v = sm.p3.scan[tid] + ((tid + off < 256) ? sm.p3.scan[tid + off] : 0u);
            __syncthreads();
            sm.p3.scan[tid] = v;
            __syncthreads();
        }
        u32 total = sm.p3.scan[0];
        u32 carry = (tid < 255) ? sm.p3.scan[tid + 1] : 0u;
        u32 sfx[4];
        sfx[3] = carry + h[3];
        sfx[2] = sfx[3] + h[2];
        sfx[1] = sfx[2] + h[1];
        sfx[0] = sfx[1] + h[0];
#pragma unroll
        for (int i = 0; i < 4; ++i) sm.p3.hist[4 * tid + i] = sfx[i];
        __syncthreads();

        u32 target = total < (u32)TOPK_N ? total : (u32)TOPK_N;
        if (target > 0) {
#pragma unroll
            for (int i = 0; i < 4; ++i) {
                int b = 4 * tid + i;
                u32 sb = sm.p3.hist[b];
                u32 snext = (b < 1023) ? sm.p3.hist[b + 1] : 0u;
                if (sb >= target && snext < target) sm.p3.meta[1] = b;  // unique writer
            }
        }
        __syncthreads();
        const int B = sm.p3.meta[1];

        // compact survivors (bucket >= B); order-free, exact ranks computed below
        for (int t = tid; t < KM; t += 256) {
            u64 k = sm.p3.keys[t];
            if (k && bucket_of(k) >= B) {
                int idx = atomicAdd(&sm.p3.meta[0], 1);
                if (idx < SURV_CAP) sm.p3.surv[idx] = k;
            }
        }
        __syncthreads();
        const int Sn = sm.p3.meta[0];

        if (Sn <= SURV_CAP) {
            for (int s = tid; s < Sn; s += 256) {
                u64 x = sm.p3.surv[s];
                int rank = 0;
                for (int i = 0; i < Sn; ++i) rank += (sm.p3.surv[i] > x) ? 1 : 0;
                if (rank < TOPK_N) write_row(outp, boxes, scores, x, rank, f32m);
            }
        } else {
            // pathological fallback: rank survivors against all keys
            for (int t = tid; t < KM; t += 256) {
                u64 x = sm.p3.keys[t];
                if (x && bucket_of(x) >= B) {
                    int rank = 0;
                    for (int i = 0; i < KM; ++i) rank += (sm.p3.keys[i] > x) ? 1 : 0;
                    if (rank < TOPK_N) write_row(outp, boxes, scores, x, rank, f32m);
                }
            }
        }
    }
}

extern "C" void kernel_launch(void* const* d_in, const int* in_sizes, int n_in,
                              void* d_out, int out_size, void* d_ws, size_t ws_size,
                              hipStream_t stream) {
    const void* boxes = d_in[0];
    const void* scores = d_in[1];
    float* hdr = (float*)d_ws;                     // 160 f32 partials at [0, 640)
    u32* bars = (u32*)((char*)d_ws + 768);         // 2 barrier counters at [768, 776)
    u64* cand = (u64*)((char*)d_ws + 1024);        // 8000 u64 candidate slots

    hipMemsetAsync(bars, 0, 16, stream);           // graph-legal memset node
    k_all<<<dim3(K_N), dim3(256), 0, stream>>>(boxes, scores, hdr, bars, cand, d_out);
}